// Round 6
// baseline (165.154 us; speedup 1.0000x reference)
//
#include <hip/hip_runtime.h>
#include <hip/hip_bf16.h>
#include <math.h>

#define BB 8
#define TT 2048
#define CC 1024
#define HH 64
#define BT (BB * TT)   // 16384 rows

typedef __attribute__((ext_vector_type(8))) short short8;   // bf16 x8 MFMA frag
typedef __attribute__((ext_vector_type(4))) float floatx4;  // MFMA acc

static __device__ inline ushort f2bf(float f) {
    __hip_bfloat16 h = __float2bfloat16(f);
    return *reinterpret_cast<ushort*>(&h);
}
static __device__ inline unsigned int f2bf2(float lo, float hi) {
    __hip_bfloat162 h = __float22bfloat162_rn(make_float2(lo, hi));
    return *reinterpret_cast<unsigned int*>(&h);
}
static __device__ inline float bf2f(ushort u) {
    union { unsigned int i; float f; } c;
    c.i = ((unsigned int)u) << 16;
    return c.f;
}

// ---------------------------------------------------------------------------
// Kernel 0: W prep (coalesced).  W[k][n] fp32 -> WbT[m][n][k] bf16.
// ---------------------------------------------------------------------------
__global__ __launch_bounds__(256) void wprep_kernel(
    const float* __restrict__ Wq, const float* __restrict__ Wk,
    const float* __restrict__ Wv, ushort* __restrict__ WbT)
{
    __shared__ float ws_[64 * 65];
    const int m  = blockIdx.x >> 4;          // 0..2
    const int kb = (blockIdx.x & 15) * 64;   // 0..960
    const float* W = (m == 0) ? Wq : (m == 1) ? Wk : Wv;
    const int t  = threadIdx.x;
    const int lr = t >> 4, lc = (t & 15) * 4;
    #pragma unroll
    for (int i = 0; i < 4; ++i) {
        const int row = lr + i * 16;
        float4 v = *(const float4*)&W[(size_t)(kb + row) * HH + lc];
        ws_[row * 65 + lc + 0] = v.x; ws_[row * 65 + lc + 1] = v.y;
        ws_[row * 65 + lc + 2] = v.z; ws_[row * 65 + lc + 3] = v.w;
    }
    __syncthreads();
    const int n = t & 63, kseg = t >> 6;     // kseg 0..3 -> 16 k each
    union { ushort s[16]; uint4 q[2]; } u;
    #pragma unroll
    for (int j = 0; j < 16; ++j)
        u.s[j] = f2bf(ws_[(kseg * 16 + j) * 65 + n]);
    ushort* dst = &WbT[(size_t)(m * 64 + n) * 1024 + kb + kseg * 16];
    *(uint4*)&dst[0] = u.q[0];
    *(uint4*)&dst[8] = u.q[1];
}

// ---------------------------------------------------------------------------
// Kernel 1: QKV, TRANSPOSED-MFMA rewrite: out^T = mfma(A=W^T, B=x^T).
// B-operand lane map (lane=col, regs=8 consecutive k) == a per-lane
// CONTIGUOUS 32B read of global x -> NO LDS, NO transpose, NO barriers.
// A-frags use the identical WbT expression as before.  Waves independent;
// depth-2 x prefetch + depth-1 W prefetch survive (nothing drains vmcnt).
// __launch_bounds__(256,2) so the allocator keeps prefetch regs live
// (round-3's 96-VGPR load-sinking failure mode).
// MFMA call order over (it,p) identical to old kernel -> bit-exact outputs.
// ---------------------------------------------------------------------------
__global__ __launch_bounds__(256, 2) void qkv_kernel(
    const float* __restrict__ x, const ushort* __restrict__ WbT,
    ushort* __restrict__ qb, ushort* __restrict__ kbS, ushort* __restrict__ vS)
{
    const int t    = threadIdx.x;
    const int w    = t >> 6;
    const int lane = t & 63;
    const int l16  = lane & 15;
    const int quad = lane >> 4;

    const int rows0 = blockIdx.x * 32 + (w >> 1) * 16;  // this wave's 16 x-rows
    const int ct0   = (w & 1) * 6;                      // this wave's 6 col-tiles

    // per-lane x pointer: row = rows0 + l16, k base = quad*8
    const float* xr = &x[(size_t)(rows0 + l16) * CC + quad * 8];
    const ushort* wb = &WbT[(size_t)l16 * 1024 + quad * 8];

    floatx4 acc[6];
    #pragma unroll
    for (int c = 0; c < 6; ++c) acc[c] = (floatx4){0.f, 0.f, 0.f, 0.f};

    // ---- x double prefetch: xcA holds even iters, xcB odd ----
    float4 xcA[2][2], xcB[2][2];
    #pragma unroll
    for (int p = 0; p < 2; ++p) {
        xcA[p][0] = *(const float4*)&xr[p * 32 + 0];
        xcA[p][1] = *(const float4*)&xr[p * 32 + 4];
        xcB[p][0] = *(const float4*)&xr[64 + p * 32 + 0];
        xcB[p][1] = *(const float4*)&xr[64 + p * 32 + 4];
    }

    // ---- A (W^T) ping-pong prefetch ----
    short8 afA[2][6], afB[2][6];
    #pragma unroll
    for (int p = 0; p < 2; ++p)
        #pragma unroll
        for (int c = 0; c < 6; ++c)
            afA[p][c] = *(const short8*)&wb[(size_t)(ct0 + c) * 16384 + p * 32];

    auto body = [&](int it, float4 (&xc)[2][2], short8 (&aCur)[2][6], short8 (&aNxt)[2][6]) {
        // consume x -> B-frags
        short8 bx[2];
        #pragma unroll
        for (int p = 0; p < 2; ++p) {
            union { unsigned int u[4]; short8 s; } cv;
            cv.u[0] = f2bf2(xc[p][0].x, xc[p][0].y);
            cv.u[1] = f2bf2(xc[p][0].z, xc[p][0].w);
            cv.u[2] = f2bf2(xc[p][1].x, xc[p][1].y);
            cv.u[3] = f2bf2(xc[p][1].z, xc[p][1].w);
            bx[p] = cv.s;
        }
        // refill this x buffer with iter it+2 (regs just freed)
        if (it + 2 < 16) {
            #pragma unroll
            for (int p = 0; p < 2; ++p) {
                xc[p][0] = *(const float4*)&xr[(it + 2) * 64 + p * 32 + 0];
                xc[p][1] = *(const float4*)&xr[(it + 2) * 64 + p * 32 + 4];
            }
        }
        // A prefetch for it+1
        if (it + 1 < 16) {
            #pragma unroll
            for (int p = 0; p < 2; ++p)
                #pragma unroll
                for (int c = 0; c < 6; ++c)
                    aNxt[p][c] = *(const short8*)&wb[(size_t)(ct0 + c) * 16384
                                                     + (it + 1) * 64 + p * 32];
        }
        __builtin_amdgcn_s_setprio(1);
        #pragma unroll
        for (int p = 0; p < 2; ++p)
            #pragma unroll
            for (int c = 0; c < 6; ++c)
                acc[c] = __builtin_amdgcn_mfma_f32_16x16x32_bf16(aCur[p][c], bx[p], acc[c], 0, 0, 0);
        __builtin_amdgcn_s_setprio(0);
    };

    #pragma unroll 1
    for (int it2 = 0; it2 < 16; it2 += 4) {
        body(it2 + 0, xcA, afA, afB);
        body(it2 + 1, xcB, afB, afA);
        body(it2 + 2, xcA, afA, afB);
        body(it2 + 3, xcB, afB, afA);
    }

    // ---- epilogue: D row = h-sub (quad*4+reg), col = x-row (l16) ----
    const size_t tile = (size_t)(rows0 >> 6) * 4096;
    #pragma unroll
    for (int c = 0; c < 6; ++c) {
        const int ct    = ct0 + c;
        const int mtype = ct >> 2;
        const int nn    = ct & 3;
        if (mtype == 0) {                       // q: row-major [row][h], /8 folded
            uint2 u;
            u.x = f2bf2(acc[c][0] * 0.125f, acc[c][1] * 0.125f);
            u.y = f2bf2(acc[c][2] * 0.125f, acc[c][3] * 0.125f);
            *(uint2*)&qb[(size_t)(rows0 + l16) * HH + nn * 16 + quad * 4] = u;
        } else if (mtype == 1) {                // K swizzled (B-frag order)
            // key = rows0+l16 ; h = nn*16 + quad*4 + reg
            const int ckey  = (rows0 >> 4) & 3;
            const int p     = nn >> 1;
            const int quadP = (nn * 2 + (quad >> 1)) & 3;
            const int j0    = (quad & 1) * 4;
            uint2 u;
            u.x = f2bf2(acc[c][0], acc[c][1]);
            u.y = f2bf2(acc[c][2], acc[c][3]);
            *(uint2*)&kbS[tile + (size_t)((ckey * 2 + p) * 64 + quadP * 16 + l16) * 8 + j0] = u;
        } else {                                // V swizzled (B-frag order)
            // key = rows0+l16 ; h = nn*16 + quad*4 + reg
            const int pv = (rows0 >> 5) & 1;
            const int qv = ((rows0 >> 4) & 1) * 2 + (l16 >> 3);
            const int jv = l16 & 7;
            #pragma unroll
            for (int reg = 0; reg < 4; ++reg)
                vS[tile + (size_t)((nn * 2 + pv) * 64 + qv * 16 + quad * 4 + reg) * 8 + jv]
                    = f2bf(acc[c][reg]);
        }
    }
}

// ---------------------------------------------------------------------------
// Kernel 2: split-K MFMA flash attention (barrier-free, swapped QK^T,
// transposed packed Opart).  Unchanged this round.
// ---------------------------------------------------------------------------
__global__ __launch_bounds__(256) void attn_kernel(
    const ushort* __restrict__ qb, const ushort* __restrict__ kbS,
    const ushort* __restrict__ vS, ushort* __restrict__ Opart,
    float* __restrict__ ml)
{
    __shared__ __align__(16) ushort P[4][16 * 72];   // per-wave P tile

    const int t    = threadIdx.x;
    const int w    = t >> 6;
    const int lane = t & 63;
    const int l16  = lane & 15;
    const int quad = lane >> 4;

    const int b   = blockIdx.x & 7;
    const int idx = blockIdx.x >> 3;   // 0..79, heavy-first
    int qt, part, np;
    if (idx < 32)      { qt = 31 - (idx >> 2); part = idx & 3; np = 4; }
    else if (idx < 56) { const int u = idx - 32; const int g = u / 3;
                         qt = 23 - g; part = u - g * 3; np = 3; }
    else if (idx < 72) { const int u = idx - 56; qt = 15 - (u >> 1); part = u & 1; np = 2; }
    else               { qt = 7 - (idx - 72); part = 0; np = 1; }
    const int ntiles = qt + 1;
    const int ktb = (part * ntiles) / np;
    const int kte = ((part + 1) * ntiles) / np;

    const ushort* ktile0 = kbS + (size_t)(b * 32) * 4096;
    const ushort* vtile0 = vS  + (size_t)(b * 32) * 4096;

    // Q frags (B-operand of swapped QK^T; B-frag lane map == A-frag map)
    short8 qf[2];
    {
        const ushort* qrow = qb + ((size_t)b * TT + qt * 64 + w * 16) * HH;
        qf[0] = *(const short8*)&qrow[l16 * HH + quad * 8];
        qf[1] = *(const short8*)&qrow[l16 * HH + 32 + quad * 8];
    }
    short8 ones;
    #pragma unroll
    for (int i = 0; i < 8; ++i) ones[i] = (short)0x3F80;   // bf16 1.0

    floatx4 o[4], osum;
    #pragma unroll
    for (int c = 0; c < 4; ++c) o[c] = (floatx4){0.f, 0.f, 0.f, 0.f};
    osum = (floatx4){0.f, 0.f, 0.f, 0.f};

    ushort* Pw = &P[w][0];

    for (int kt = ktb; kt < kte; ++kt) {
        const ushort* kg = ktile0 + (size_t)kt * 4096;
        const ushort* vg = vtile0 + (size_t)kt * 4096;

        // ---- K frags from global (L2-hit, frag-ordered) ----
        short8 kf[4][2];
        #pragma unroll
        for (int c = 0; c < 4; ++c)
            #pragma unroll
            for (int p = 0; p < 2; ++p)
                kf[c][p] = *(const short8*)&kg[(size_t)(((c * 2 + p) * 64) + lane) * 8];

        // ---- S^T = K Q^T (operand-swapped): row=key chunk, col=q ----
        floatx4 s[4];
        #pragma unroll
        for (int c = 0; c < 4; ++c) s[c] = (floatx4){0.f, 0.f, 0.f, 0.f};
        __builtin_amdgcn_s_setprio(1);
        #pragma unroll
        for (int c = 0; c < 4; ++c)
            #pragma unroll
            for (int p = 0; p < 2; ++p)
                s[c] = __builtin_amdgcn_mfma_f32_16x16x32_bf16(kf[c][p], qf[p], s[c], 0, 0, 0);
        __builtin_amdgcn_s_setprio(0);

        // ---- V frags (issued while exp/P path runs) ----
        short8 vf[4][2];
        #pragma unroll
        for (int c = 0; c < 4; ++c)
            #pragma unroll
            for (int p = 0; p < 2; ++p)
                vf[c][p] = *(const short8*)&vg[(size_t)(((c * 2 + p) * 64) + lane) * 8];

        // ---- causal mask (roles swapped: key from reg, q from l16) ----
        if (kt == ntiles - 1) {
            const int key0 = kt * 64 + quad * 4;
            const int qrow = qt * 64 + w * 16 + l16;
            #pragma unroll
            for (int c = 0; c < 4; ++c)
                #pragma unroll
                for (int reg = 0; reg < 4; ++reg)
                    if (key0 + c * 16 + reg > qrow) s[c][reg] = -1e30f;
        }

        // ---- P = exp(s^T) -> packed bf16 -> LDS row q=l16, keys contiguous ----
        #pragma unroll
        for (int c = 0; c < 4; ++c) {
            uint2 u;
            u.x = f2bf2(__expf(s[c][0]), __expf(s[c][1]));
            u.y = f2bf2(__expf(s[c][2]), __expf(s[c][3]));
            *(uint2*)&Pw[l16 * 72 + c * 16 + quad * 4] = u;
        }

        short8 pf[2];
        pf[0] = *(const short8*)&Pw[l16 * 72 + quad * 8];
        pf[1] = *(const short8*)&Pw[l16 * 72 + 32 + quad * 8];

        // ---- O += P V ; l += P * ones ----
        __builtin_amdgcn_s_setprio(1);
        #pragma unroll
        for (int p = 0; p < 2; ++p) {
            #pragma unroll
            for (int c = 0; c < 4; ++c)
                o[c] = __builtin_amdgcn_mfma_f32_16x16x32_bf16(pf[p], vf[c][p], o[c], 0, 0, 0);
            osum = __builtin_amdgcn_mfma_f32_16x16x32_bf16(pf[p], ones, osum, 0, 0, 0);
        }
        __builtin_amdgcn_s_setprio(0);
    }

    // ---- write partial TRANSPOSED: Opart[unit][col][row], packed b64 ----
    const size_t ub = (size_t)blockIdx.x * 4096;
    const int rbase = w * 16 + quad * 4;
    #pragma unroll
    for (int c = 0; c < 4; ++c) {
        uint2 u;
        u.x = f2bf2(o[c][0], o[c][1]);
        u.y = f2bf2(o[c][2], o[c][3]);
        *(uint2*)&Opart[ub + (size_t)(c * 16 + l16) * 64 + rbase] = u;
    }
    if (l16 == 0) {
        #pragma unroll
        for (int reg = 0; reg < 4; ++reg)
            ml[(size_t)blockIdx.x * 64 + rbase + reg] = osum[reg];
    }
}

// ---------------------------------------------------------------------------
// Kernel 3: merge partials (transposed Opart).  out = (sum O_p) / (sum l_p).
// ---------------------------------------------------------------------------
__global__ __launch_bounds__(256) void merge_kernel(
    const ushort* __restrict__ Opart, const float* __restrict__ ml,
    float* __restrict__ out)
{
    const int t    = threadIdx.x;
    const int gw   = blockIdx.x * 4 + (t >> 6);   // 0..2047
    const int lane = t & 63;                      // = output col
    const int b    = gw >> 8;
    const int v    = gw & 255;
    const int qt   = v >> 3;
    const int oct  = v & 7;

    int base, np;
    if (qt >= 24)      { base = (31 - qt) * 4;      np = 4; }
    else if (qt >= 16) { base = 32 + (23 - qt) * 3; np = 3; }
    else if (qt >= 8)  { base = 56 + (15 - qt) * 2; np = 2; }
    else               { base = 72 + (7 - qt);      np = 1; }

    float* obase = out + ((size_t)b * TT + qt * 64) * HH;

    #pragma unroll
    for (int rg = 0; rg < 2; ++rg) {
        const int row0 = oct * 8 + rg * 4;
        float dx = 0.f, dy = 0.f, dz = 0.f, dw = 0.f;
        float ax = 0.f, ay = 0.f, az = 0.f, aw = 0.f;
        for (int p = 0; p < np; ++p) {
            const int unit = (base + p) * 8 + b;
            float4 d = *(const float4*)&ml[(size_t)unit * 64 + row0];
            dx += d.x; dy += d.y; dz += d.z; dw += d.w;
            ushort4 ov = *(const ushort4*)&Opart[(size_t)unit * 4096 + lane * 64 + row0];
            ax += bf2f(ov.x); ay += bf2f(ov.y); az += bf2f(ov.z); aw += bf2f(ov.w);
        }
        obase[(size_t)(row0 + 0) * HH + lane] = ax / dx;
        obase[(size_t)(row0 + 1) * HH + lane] = ay / dy;
        obase[(size_t)(row0 + 2) * HH + lane] = az / dz;
        obase[(size_t)(row0 + 3) * HH + lane] = aw / dw;
    }
}

// ---------------------------------------------------------------------------
extern "C" void kernel_launch(void* const* d_in, const int* in_sizes, int n_in,
                              void* d_out, int out_size, void* d_ws, size_t ws_size,
                              hipStream_t stream)
{
    (void)in_sizes; (void)n_in; (void)out_size; (void)ws_size;
    const float* x  = (const float*)d_in[0];
    const float* Wq = (const float*)d_in[1];
    const float* Wk = (const float*)d_in[2];
    const float* Wv = (const float*)d_in[3];
    float* outp = (float*)d_out;

    // ws: WbT 384K | qb 2M | kbS 2M | vS 2M | Opart 5.24M | ml 160K (~11.8 MB)
    char* base = (char*)d_ws;
    ushort* WbT   = (ushort*)(base);
    ushort* qbuf  = (ushort*)(base + 393216);
    ushort* kbS   = qbuf + (size_t)BT * HH;
    ushort* vSb   = kbS + (size_t)BT * HH;
    ushort* Opart = vSb + (size_t)BT * HH;
    float*  ml    = (float*)((char*)Opart + (size_t)640 * 4096 * 2);

    wprep_kernel<<<dim3(48),  256, 0, stream>>>(Wq, Wk, Wv, WbT);
    qkv_kernel  <<<dim3(512), 256, 0, stream>>>(x, WbT, qbuf, kbS, vSb);
    attn_kernel <<<dim3(640), 256, 0, stream>>>(qbuf, kbS, vSb, Opart, ml);
    merge_kernel<<<dim3(512), 256, 0, stream>>>(Opart, ml, outp);
}